// Round 3
// baseline (3833.488 us; speedup 1.0000x reference)
//
#include <hip/hip_runtime.h>

namespace {

constexpr int NX = 384, NY = 384, NZ = 48;
constexpr int PLN = NX * NY;
constexpr int NXU = NX + 1;
constexpr float RDX = 1.0f / 1000.0f;
constexpr float RDY = 1.0f / 1000.0f;
constexpr float RDZ = 49.0f;              // 1/DZ, DZ = 1/(NZ+1)
constexpr float PREFc = 100000.0f, RDc = 287.0f, Gc = 9.81f;
constexpr float K_RP = RDc / PREFc;

constexpr int SZ_U = NZ * NY * NXU;
constexpr int SZ_V = NZ * (NY + 1) * NX;
constexpr int SZ_W = (NZ - 1) * PLN;
constexpr int SZ_T = NZ * PLN;
constexpr int SZ_M = NZ * PLN;
constexpr int SZ_P = (NZ - 1) * PLN;
constexpr int SZ_STATE = SZ_U + SZ_V + SZ_W + SZ_T + SZ_M + SZ_P;

constexpr int CH = 12;                    // k-levels per thread

__device__ __forceinline__ float frcp(float x) { return __builtin_amdgcn_rcpf(x); }
__device__ __forceinline__ float pow14(float x) {
    // x^1.4 = exp2(1.4 * log2(x)); v_log_f32/v_exp_f32 are base-2
    return __builtin_amdgcn_exp2f(1.4f * __builtin_amdgcn_logf(x));
}

__global__ __launch_bounds__(128, 2)
void rhs_fused(
    const float* __restrict__ Us, const float* __restrict__ Vs, const float* __restrict__ Ws,
    const float* __restrict__ Ts, const float* __restrict__ Ms, const float* __restrict__ Ps,
    const float* __restrict__ Phit, const float* __restrict__ Phis,
    const float* __restrict__ Pt,   const float* __restrict__ Psrf,
    const float* __restrict__ U0, const float* __restrict__ V0, const float* __restrict__ W0,
    const float* __restrict__ T0, const float* __restrict__ M0, const float* __restrict__ P0,
    float* __restrict__ Uo, float* __restrict__ Vo, float* __restrict__ Wo,
    float* __restrict__ To, float* __restrict__ Mo, float* __restrict__ Po,
    const int* __restrict__ dtp, float coef)
{
    const int i  = blockIdx.x * 128 + threadIdx.x;
    const int j  = blockIdx.y;
    const int k0 = blockIdx.z * CH;
    const float c = coef * (float)(*dtp);

    // wrapped neighbor columns/rows (computed once)
    const int im = (i == 0) ? NX - 1 : i - 1;
    const int ip = (i == NX - 1) ? 0 : i + 1;
    const int jm = (j == 0) ? NY - 1 : j - 1;
    const int jp = (j == NY - 1) ? 0 : j + 1;

    const int pC  = j * NX + i,  pW  = j * NX + im, pE  = j * NX + ip;
    const int pS  = jm * NX + i, pN  = jp * NX + i;
    const int pSW = jm * NX + im, pNW = jp * NX + im, pSE = jm * NX + ip;
    const int pWW = (i >= 2) ? (j * NX + i - 2) : (j * NX + NX - 2 + i);   // dummy at i==0
    const int pSS = (j >= 2) ? ((j - 2) * NX + i) : ((NY - 2 + j) * NX + i); // dummy at j==0

    // staggered U column indices (row-major with NXU cols)
    const int uq_C  = j * NXU + i;
    const int uq_p1 = j * NXU + i + 1;
    const int uq_m1 = j * NXU + ((i == 0) ? NX : (i - 1));
    const int uq_S  = jm * NXU + i;
    const int uq_N  = jp * NXU + i;
    // MUX plane-offset pairs for staggered u points
    const int pm1a = (i == 0) ? pW : pWW, pm1b = (i == 0) ? pC : pW;
    const int pp1a = pC,                  pp1b = (i == NX - 1) ? (j * NX) : pE;

    // staggered V indices (plane-like, rows 0..NY)
    const int vq_C  = j * NX + i;
    const int vq_p1 = (j + 1) * NX + i;
    const int vq_m1 = ((j == 0) ? NY : (j - 1)) * NX + i;
    const int vq_W  = j * NX + im;
    const int vq_E  = j * NX + ip;
    const int qm1a = (j == 0) ? pS : pSS, qm1b = (j == 0) ? pC : pS;
    const int qp1a = pC,                  qp1b = (j == NY - 1) ? i : pN;

    // ---- plane-offset accessors ----
    auto MU   = [&](int kk, int pix) -> float { return Ms[kk * PLN + pix]; };
    auto TH   = [&](int kk, int pix) -> float {
        const int id = kk * PLN + pix; return Ts[id] * frcp(Ms[id]); };
    auto PHIP = [&](int kk, int pix) -> float {
        if (kk <= 0)  return Phit[pix];
        if (kk >= NZ) return Phis[pix];
        return Ps[(kk - 1) * PLN + pix]; };
    auto ALPH = [&](int kk, int pix) -> float {
        return -(PHIP(kk + 1, pix) - PHIP(kk, pix)) * RDZ * frcp(MU(kk, pix)); };
    auto PRS  = [&](int kk, int pix) -> float {
        return PREFc * pow14(K_RP * TH(kk, pix) * frcp(ALPH(kk, pix))); };
    auto PPAD = [&](int kh, int pix) -> float {
        if (kh <= 0)      return Pt[pix];
        if (kh >= NZ + 1) return Psrf[pix];
        return PRS(kh - 1, pix); };
    auto OMH  = [&](int m, int pix) -> float {   // Omega at half-level m (0..NZ-2)
        const float a0 = ALPH(m, pix), a1 = ALPH(m + 1, pix);
        const float mz = 0.5f * (MU(m, pix) + MU(m + 1, pix));
        return -Ws[m * PLN + pix] * Gc * frcp(0.5f * (a0 + a1) * mz); };
    auto OMP  = [&](int kk, int pix) -> float {  // pad_z(Omega), levels 0..NZ
        if (kk <= 0 || kk >= NZ) return 0.0f;
        return OMH(kk - 1, pix); };
    auto UFp  = [&](int kk, int uq) -> float { return Us[kk * NY * NXU + uq]; };
    auto VFp  = [&](int kk, int vq) -> float { return Vs[kk * (NY + 1) * NX + vq]; };
    auto WFp  = [&](int kk, int pix) -> float { return Ws[kk * PLN + pix]; };
    auto UUp  = [&](int kk, int uq, int pa, int pb) -> float {
        return UFp(kk, uq) * frcp(0.5f * (MU(kk, pa) + MU(kk, pb))); };
    auto VVp  = [&](int kk, int vq, int pa, int pb) -> float {
        return VFp(kk, vq) * frcp(0.5f * (MU(kk, pa) + MU(kk, pb))); };
    auto WWp  = [&](int kk, int pix) -> float {
        return WFp(kk, pix) * frcp(0.5f * (MU(kk, pix) + MU(kk + 1, pix))); };

    // ---- general (rare-lane) R_U at staggered column II ----
    auto R_U_any = [&](int kk, int II) -> float {
        const int Im1 = (II == 0) ? NX : II - 1;
        const int Ip1 = (II == NX) ? 0 : II + 1;
        const int xa = (II == 0) ? NX - 1 : II - 1;
        const int xb = (II == NX) ? 0 : II;
        const int pa = j * NX + xa, pb = j * NX + xb;
        const int pam = jm * NX + xa, pbm = jm * NX + xb;
        const int pap = jp * NX + xa, pbp = jp * NX + xb;
        auto UUx = [&](int kz, int Iq) -> float {
            const int a2 = (Iq == 0) ? NX - 1 : Iq - 1;
            const int b2 = (Iq == NX) ? 0 : Iq;
            return Us[kz * NY * NXU + j * NXU + Iq] *
                   frcp(0.5f * (MU(kz, j * NX + a2) + MU(kz, j * NX + b2)));
        };
        const float U_m1 = Us[kk * NY * NXU + j * NXU + Im1];
        const float U_0  = Us[kk * NY * NXU + j * NXU + II];
        const float U_p1 = Us[kk * NY * NXU + j * NXU + Ip1];
        const float u_m1 = UUx(kk, Im1), u_0 = UUx(kk, II), u_p1 = UUx(kk, Ip1);
        float r = -((U_0 + U_p1) * (u_0 + u_p1) - (U_m1 + U_0) * (u_m1 + u_0)) * 0.25f * RDX;
        const float VBj  = 0.5f * (VFp(kk, j * NX + xa) + VFp(kk, j * NX + xb));
        const float VBj1 = 0.5f * (VFp(kk, (j + 1) * NX + xa) + VFp(kk, (j + 1) * NX + xb));
        const float uyS = Us[kk * NY * NXU + jm * NXU + II] * frcp(0.5f * (MU(kk, pam) + MU(kk, pbm)));
        const float uyN = Us[kk * NY * NXU + jp * NXU + II] * frcp(0.5f * (MU(kk, pap) + MU(kk, pbp)));
        r -= (VBj1 * 0.5f * (u_0 + uyN) - VBj * 0.5f * (uyS + u_0)) * RDY;
        const float OBk  = 0.5f * (OMP(kk, pa) + OMP(kk, pb));
        const float OBk1 = 0.5f * (OMP(kk + 1, pa) + OMP(kk + 1, pb));
        const float uzk  = (kk == 0)      ? 0.5f * u_0 : 0.5f * (UUx(kk - 1, II) + u_0);
        const float uzk1 = (kk == NZ - 1) ? 0.5f * u_0 : 0.5f * (u_0 + UUx(kk + 1, II));
        r -= (OBk1 * uzk1 - OBk * uzk) * RDZ;
        const float mux = 0.5f * (MU(kk, pa) + MU(kk, pb));
        const float alx = 0.5f * (ALPH(kk, pa) + ALPH(kk, pb));
        const float dpx = (PRS(kk, pb) - PRS(kk, pa)) * RDX;
        r -= mux * alx * dpx;
        const float za = 0.25f * (PPAD(kk, pa) + PPAD(kk + 1, pa) + PPAD(kk, pb) + PPAD(kk + 1, pb));
        const float zb = 0.25f * (PPAD(kk + 1, pa) + PPAD(kk + 2, pa) + PPAD(kk + 1, pb) + PPAD(kk + 2, pb));
        const float dpz = (zb - za) * RDZ;
        const float pza = 0.5f * (PHIP(kk, pa) + PHIP(kk + 1, pa));
        const float pzb = 0.5f * (PHIP(kk, pb) + PHIP(kk + 1, pb));
        r -= dpz * (pzb - pza) * RDX;
        return r;
    };

    // ---- general (rare-lane) R_V at staggered row JJ ----
    auto R_V_any = [&](int kk, int JJ) -> float {
        const int Jm1 = (JJ == 0) ? NY : JJ - 1;
        const int Jp1 = (JJ == NY) ? 0 : JJ + 1;
        const int ya = (JJ == 0) ? NY - 1 : JJ - 1;
        const int yb = (JJ == NY) ? 0 : JJ;
        const int pa = ya * NX + i, pb = yb * NX + i;
        const int pam = ya * NX + im, pbm = yb * NX + im;
        const int pap = ya * NX + ip, pbp = yb * NX + ip;
        auto VVx = [&](int kz, int Jq) -> float {
            const int a2 = (Jq == 0) ? NY - 1 : Jq - 1;
            const int b2 = (Jq == NY) ? 0 : Jq;
            return Vs[kz * (NY + 1) * NX + Jq * NX + i] *
                   frcp(0.5f * (MU(kz, a2 * NX + i) + MU(kz, b2 * NX + i)));
        };
        const float V_m1 = Vs[kk * (NY + 1) * NX + Jm1 * NX + i];
        const float V_0  = Vs[kk * (NY + 1) * NX + JJ * NX + i];
        const float V_p1 = Vs[kk * (NY + 1) * NX + Jp1 * NX + i];
        const float v_m1 = VVx(kk, Jm1), v_0 = VVx(kk, JJ), v_p1 = VVx(kk, Jp1);
        float r = -((V_0 + V_p1) * (v_0 + v_p1) - (V_m1 + V_0) * (v_m1 + v_0)) * 0.25f * RDY;
        const float UBi  = 0.5f * (UFp(kk, ya * NXU + i) + UFp(kk, yb * NXU + i));
        const float UBi1 = 0.5f * (UFp(kk, ya * NXU + i + 1) + UFp(kk, yb * NXU + i + 1));
        const float vxW = Vs[kk * (NY + 1) * NX + JJ * NX + im] * frcp(0.5f * (MU(kk, pam) + MU(kk, pbm)));
        const float vxE = Vs[kk * (NY + 1) * NX + JJ * NX + ip] * frcp(0.5f * (MU(kk, pap) + MU(kk, pbp)));
        r -= (UBi1 * 0.5f * (v_0 + vxE) - UBi * 0.5f * (vxW + v_0)) * RDX;
        const float OBk  = 0.5f * (OMP(kk, pa) + OMP(kk, pb));
        const float OBk1 = 0.5f * (OMP(kk + 1, pa) + OMP(kk + 1, pb));
        const float vzk  = (kk == 0)      ? 0.5f * v_0 : 0.5f * (VVx(kk - 1, JJ) + v_0);
        const float vzk1 = (kk == NZ - 1) ? 0.5f * v_0 : 0.5f * (v_0 + VVx(kk + 1, JJ));
        r -= (OBk1 * vzk1 - OBk * vzk) * RDZ;
        const float muy = 0.5f * (MU(kk, pa) + MU(kk, pb));
        const float aly = 0.5f * (ALPH(kk, pa) + ALPH(kk, pb));
        const float dpy = (PRS(kk, pb) - PRS(kk, pa)) * RDY;
        r -= muy * aly * dpy;
        const float za = 0.25f * (PPAD(kk, pa) + PPAD(kk + 1, pa) + PPAD(kk, pb) + PPAD(kk + 1, pb));
        const float zb = 0.25f * (PPAD(kk + 1, pa) + PPAD(kk + 2, pa) + PPAD(kk + 1, pb) + PPAD(kk + 2, pb));
        const float dpz = (zb - za) * RDZ;
        const float pza = 0.5f * (PHIP(kk, pa) + PHIP(kk + 1, pa));
        const float pzb = 0.5f * (PHIP(kk, pb) + PHIP(kk + 1, pb));
        r -= dpz * (pzb - pza) * RDY;
        return r;
    };

    #pragma unroll 2
    for (int k = k0; k < k0 + CH; ++k) {
        // ===== R_U (center column II = i) =====
        const float U_m1 = UFp(k, uq_m1), U_0 = UFp(k, uq_C), U_p1 = UFp(k, uq_p1);
        const float u_m1 = UUp(k, uq_m1, pm1a, pm1b);
        const float u_0  = UUp(k, uq_C, pW, pC);
        const float u_p1 = UUp(k, uq_p1, pp1a, pp1b);
        float rU = -((U_0 + U_p1) * (u_0 + u_p1) - (U_m1 + U_0) * (u_m1 + u_0)) * 0.25f * RDX;
        const float VBj  = 0.5f * (VFp(k, vq_W) + VFp(k, vq_C));
        const float VBj1 = 0.5f * (VFp(k, vq_W + NX) + VFp(k, vq_C + NX));
        const float u_S = UUp(k, uq_S, pSW, pS);
        const float u_N = UUp(k, uq_N, pNW, pN);
        rU -= (VBj1 * 0.5f * (u_0 + u_N) - VBj * 0.5f * (u_S + u_0)) * RDY;
        const float OBk  = 0.5f * (OMP(k, pW) + OMP(k, pC));
        const float OBk1 = 0.5f * (OMP(k + 1, pW) + OMP(k + 1, pC));
        const float uzk  = (k == 0)      ? 0.5f * u_0 : 0.5f * (UUp(k - 1, uq_C, pW, pC) + u_0);
        const float uzk1 = (k == NZ - 1) ? 0.5f * u_0 : 0.5f * (u_0 + UUp(k + 1, uq_C, pW, pC));
        rU -= (OBk1 * uzk1 - OBk * uzk) * RDZ;
        const float mux = 0.5f * (MU(k, pW) + MU(k, pC));
        const float alx = 0.5f * (ALPH(k, pW) + ALPH(k, pC));
        const float dpx = (PRS(k, pC) - PRS(k, pW)) * RDX;
        rU -= mux * alx * dpx;
        const float pzx_k  = 0.25f * (PPAD(k, pW) + PPAD(k + 1, pW) + PPAD(k, pC) + PPAD(k + 1, pC));
        const float pzx_k1 = 0.25f * (PPAD(k + 1, pW) + PPAD(k + 2, pW) + PPAD(k + 1, pC) + PPAD(k + 2, pC));
        const float dpzx = (pzx_k1 - pzx_k) * RDZ;
        const float phzW = 0.5f * (PHIP(k, pW) + PHIP(k + 1, pW));
        const float phzC = 0.5f * (PHIP(k, pC) + PHIP(k + 1, pC));
        rU -= dpzx * (phzC - phzW) * RDX;

        // ===== R_V (center row JJ = j) =====
        const float V_m1 = VFp(k, vq_m1), V_0 = VFp(k, vq_C), V_p1 = VFp(k, vq_p1);
        const float v_m1 = VVp(k, vq_m1, qm1a, qm1b);
        const float v_0  = VVp(k, vq_C, pS, pC);
        const float v_p1 = VVp(k, vq_p1, qp1a, qp1b);
        float rV = -((V_0 + V_p1) * (v_0 + v_p1) - (V_m1 + V_0) * (v_m1 + v_0)) * 0.25f * RDY;
        const float UBi  = 0.5f * (UFp(k, uq_S) + UFp(k, uq_C));
        const float UBi1 = 0.5f * (UFp(k, uq_S + 1) + UFp(k, uq_C + 1));
        const float v_W = VVp(k, vq_W, pSW, pW);
        const float v_E = VVp(k, vq_E, pSE, pE);
        rV -= (UBi1 * 0.5f * (v_0 + v_E) - UBi * 0.5f * (v_W + v_0)) * RDX;
        const float OBVk  = 0.5f * (OMP(k, pS) + OMP(k, pC));
        const float OBVk1 = 0.5f * (OMP(k + 1, pS) + OMP(k + 1, pC));
        const float vzk  = (k == 0)      ? 0.5f * v_0 : 0.5f * (VVp(k - 1, vq_C, pS, pC) + v_0);
        const float vzk1 = (k == NZ - 1) ? 0.5f * v_0 : 0.5f * (v_0 + VVp(k + 1, vq_C, pS, pC));
        rV -= (OBVk1 * vzk1 - OBVk * vzk) * RDZ;
        const float muy = 0.5f * (MU(k, pS) + MU(k, pC));
        const float aly = 0.5f * (ALPH(k, pS) + ALPH(k, pC));
        const float dpy = (PRS(k, pC) - PRS(k, pS)) * RDY;
        rV -= muy * aly * dpy;
        const float pzy_k  = 0.25f * (PPAD(k, pS) + PPAD(k + 1, pS) + PPAD(k, pC) + PPAD(k + 1, pC));
        const float pzy_k1 = 0.25f * (PPAD(k + 1, pS) + PPAD(k + 2, pS) + PPAD(k + 1, pC) + PPAD(k + 2, pC));
        const float dpzy = (pzy_k1 - pzy_k) * RDZ;
        const float phzS = 0.5f * (PHIP(k, pS) + PHIP(k + 1, pS));
        rV -= dpzy * (phzC - phzS) * RDY;

        // ===== R_Theta =====
        const float th0 = TH(k, pC);
        float rT = -(UFp(k, uq_p1) * 0.5f * (th0 + TH(k, pE))
                   - UFp(k, uq_C)  * 0.5f * (TH(k, pW) + th0)) * RDX
                   -(VFp(k, vq_p1) * 0.5f * (th0 + TH(k, pN))
                   - VFp(k, vq_C)  * 0.5f * (TH(k, pS) + th0)) * RDY;
        const float Hk  = (k == 0)      ? 0.0f : OMP(k, pC)     * 0.5f * (TH(k - 1, pC) + th0);
        const float Hk1 = (k == NZ - 1) ? 0.0f : OMP(k + 1, pC) * 0.5f * (th0 + TH(k + 1, pC));
        rT -= (Hk1 - Hk) * RDZ;

        // ===== R_Mu =====
        const float rM = -(UFp(k, uq_p1) - UFp(k, uq_C)) * RDX
                         -(VFp(k, vq_p1) - VFp(k, vq_C)) * RDY
                         -(OMP(k + 1, pC) - OMP(k, pC)) * RDZ;

        // ===== stores (center) =====
        const int idc = k * PLN + pC;
        To[idc] = T0[idc] + c * rT;
        Mo[idc] = M0[idc] + c * rM;
        const int idu = k * NY * NXU + uq_C;
        Uo[idu] = U0[idu] + c * rU;
        const int idv = k * (NY + 1) * NX + vq_C;
        Vo[idv] = V0[idv] + c * rV;

        // ===== R_W / R_Phi (half levels) =====
        if (k < NZ - 1) {
            const float muzC = 0.5f * (MU(k, pC) + MU(k + 1, pC));
            const float rmuz = frcp(muzC);
            const float w_0 = WFp(k, pC) * rmuz;
            const float w_W = WWp(k, pW), w_E = WWp(k, pE);
            const float w_S = WWp(k, pS), w_N = WWp(k, pN);
            const float Uzi  = 0.5f * (UFp(k, uq_C) + UFp(k + 1, uq_C));
            const float Uzi1 = 0.5f * (UFp(k, uq_p1) + UFp(k + 1, uq_p1));
            float rW = -(Uzi1 * 0.5f * (w_0 + w_E) - Uzi * 0.5f * (w_W + w_0)) * RDX;
            const float Vzj  = 0.5f * (VFp(k, vq_C) + VFp(k + 1, vq_C));
            const float Vzj1 = 0.5f * (VFp(k, vq_p1) + VFp(k + 1, vq_p1));
            rW -= (Vzj1 * 0.5f * (w_0 + w_N) - Vzj * 0.5f * (w_S + w_0)) * RDY;
            const float OZk  = 0.5f * (OMP(k, pC) + OMP(k + 1, pC));
            const float OZk1 = 0.5f * (OMP(k + 1, pC) + OMP(k + 2, pC));
            const float wzk  = (k == 0)      ? 0.5f * w_0 : 0.5f * (WWp(k - 1, pC) + w_0);
            const float wzk1 = (k == NZ - 2) ? 0.5f * w_0 : 0.5f * (w_0 + WWp(k + 1, pC));
            rW -= (OZk1 * wzk1 - OZk * wzk) * RDZ;
            rW += Gc * ((PRS(k + 1, pC) - PRS(k, pC)) * RDZ - muzC);

            const float ubz = 0.25f * (u_0 + u_p1
                             + UUp(k + 1, uq_C, pW, pC) + UUp(k + 1, uq_p1, pp1a, pp1b));
            const float dfx = (Ps[k * PLN + pE] - Ps[k * PLN + pW]) * (0.5f * RDX);
            const float vbz = 0.25f * (v_0 + v_p1
                             + VVp(k + 1, vq_C, pS, pC) + VVp(k + 1, vq_p1, qp1a, qp1b));
            const float dfy = (Ps[k * PLN + pN] - Ps[k * PLN + pS]) * (0.5f * RDY);
            const float om  = OMP(k + 1, pC) * rmuz;
            const float dfz = (PHIP(k + 2, pC) - PHIP(k, pC)) * (0.5f * RDZ);
            const float rP = -ubz * dfx - vbz * dfy - om * dfz + Gc * w_0;

            Wo[idc] = W0[idc] + c * rW;
            Po[idc] = P0[idc] + c * rP;
        }

        // ===== rare-lane extra staggered columns =====
        if (i == NX - 1) {
            Uo[idu + 1] = U0[idu + 1] + c * R_U_any(k, NX);
        }
        if (j == NY - 1) {
            const int idv2 = k * (NY + 1) * NX + NY * NX + i;
            Vo[idv2] = V0[idv2] + c * R_V_any(k, NY);
        }
    }
}

} // anonymous namespace

extern "C" void kernel_launch(void* const* d_in, const int* in_sizes, int n_in,
                              void* d_out, int out_size, void* d_ws, size_t ws_size,
                              hipStream_t stream)
{
    (void)in_sizes; (void)n_in; (void)out_size; (void)ws_size;

    const float* U0   = (const float*)d_in[0];
    const float* V0   = (const float*)d_in[1];
    const float* W0   = (const float*)d_in[2];
    const float* T0   = (const float*)d_in[3];
    const float* M0   = (const float*)d_in[4];
    const float* P0   = (const float*)d_in[5];
    const float* Phit = (const float*)d_in[6];
    const float* Phis = (const float*)d_in[7];
    const float* Pt   = (const float*)d_in[8];
    const float* Psrf = (const float*)d_in[9];
    const int*   dtp  = (const int*)d_in[10];

    float* out = (float*)d_out;
    float* ws  = (float*)d_ws;

    float* outU = out;
    float* outV = outU + SZ_U;
    float* outW = outV + SZ_V;
    float* outT = outW + SZ_W;
    float* outM = outT + SZ_T;
    float* outP = outM + SZ_M;

    float* wsU = ws;
    float* wsV = wsU + SZ_U;
    float* wsW = wsV + SZ_V;
    float* wsT = wsW + SZ_W;
    float* wsM = wsT + SZ_T;
    float* wsP = wsM + SZ_M;

    const dim3 blk(128, 1, 1);
    const dim3 grd(NX / 128, NY, NZ / CH);

    const float coefs[3] = {1.0f / 3.0f, 0.5f, 1.0f};

    const float* sU[3] = {U0, outU, wsU};
    const float* sV[3] = {V0, outV, wsV};
    const float* sW[3] = {W0, outW, wsW};
    const float* sT[3] = {T0, outT, wsT};
    const float* sM[3] = {M0, outM, wsM};
    const float* sP[3] = {P0, outP, wsP};
    float* oU[3] = {outU, wsU, outU};
    float* oV[3] = {outV, wsV, outV};
    float* oW[3] = {outW, wsW, outW};
    float* oT[3] = {outT, wsT, outT};
    float* oM[3] = {outM, wsM, outM};
    float* oP[3] = {outP, wsP, outP};

    for (int s = 0; s < 3; ++s) {
        rhs_fused<<<grd, blk, 0, stream>>>(
            sU[s], sV[s], sW[s], sT[s], sM[s], sP[s],
            Phit, Phis, Pt, Psrf,
            U0, V0, W0, T0, M0, P0,
            oU[s], oV[s], oW[s], oT[s], oM[s], oP[s],
            dtp, coefs[s]);
    }
}

// Round 4
// 959.709 us; speedup vs baseline: 3.9944x; 3.9944x over previous
//
#include <hip/hip_runtime.h>

namespace {

constexpr int NXc = 384, NYc = 384, NZc = 48;
constexpr float RDX = 1.0f / 1000.0f;     // 1/DX
constexpr float RDY = 1.0f / 1000.0f;     // 1/DY
constexpr float RDZ = 49.0f;              // 1/DZ, DZ = 1/(NZ+1)
constexpr float PREFf = 100000.0f, RDf = 287.0f, Gf = 9.81f;
constexpr float K_RP = RDf / PREFf;

constexpr int PLN  = NYc * NXc;
constexpr int SZ_U = NZc * NYc * (NXc + 1);
constexpr int SZ_V = NZc * (NYc + 1) * NXc;
constexpr int SZ_W = (NZc - 1) * PLN;
constexpr int SZ_T = NZc * PLN;
constexpr int SZ_M = NZc * PLN;
constexpr int SZ_P = (NZc - 1) * PLN;
constexpr int SZ_STATE = SZ_U + SZ_V + SZ_W + SZ_T + SZ_M + SZ_P;

__device__ __forceinline__ float frcp(float x) { return __builtin_amdgcn_rcpf(x); }
__device__ __forceinline__ float pow14(float x) {
    // x^1.4 = exp2(1.4*log2(x)); v_log_f32/v_exp_f32 are base-2
    return __builtin_amdgcn_exp2f(1.4f * __builtin_amdgcn_logf(x));
}

// ---------------- prep: p (pow-heavy) and Omega, once per point ----------------
__global__ __launch_bounds__(128)
void prep_kernel(const float* __restrict__ Ts, const float* __restrict__ Ms,
                 const float* __restrict__ Ps, const float* __restrict__ Ws,
                 const float* __restrict__ Phit, const float* __restrict__ Phis,
                 float* __restrict__ prs, float* __restrict__ Omg)
{
    const int i = blockIdx.x * blockDim.x + threadIdx.x;
    const int j = blockIdx.y;
    const int k = blockIdx.z;
    if (i >= NXc) return;
    const int jix = j * NXc + i;

    auto PHIP = [&](int kk) -> float {
        if (kk <= 0)   return Phit[jix];
        if (kk >= NZc) return Phis[jix];
        return Ps[(kk - 1) * PLN + jix];
    };

    const float mu  = Ms[k * PLN + jix];
    const float ph0 = PHIP(k), ph1 = PHIP(k + 1);
    const float alpha = -(ph1 - ph0) * RDZ * frcp(mu);
    const float theta = Ts[k * PLN + jix] * frcp(mu);
    const float x  = K_RP * theta * frcp(alpha);
    prs[k * PLN + jix] = PREFf * pow14(x);

    if (k < NZc - 1) {
        const float mu1 = Ms[(k + 1) * PLN + jix];
        const float ph2 = PHIP(k + 2);
        const float alpha1 = -(ph2 - ph1) * RDZ * frcp(mu1);
        // Omega = -W*G / (bar_z(alpha) * bar_z(Mu))
        const float Om = -Ws[k * PLN + jix] * Gf *
                         frcp((0.5f * (alpha + alpha1)) * (0.5f * (mu + mu1)));
        Omg[k * PLN + jix] = Om;
    }
}

// ---------------- rhs + RK stage update ----------------
__global__ __launch_bounds__(128)
void rhs_kernel(
    const float* __restrict__ Us, const float* __restrict__ Vs, const float* __restrict__ Ws,
    const float* __restrict__ Ts, const float* __restrict__ Ms, const float* __restrict__ Ps,
    const float* __restrict__ prs, const float* __restrict__ Omg,
    const float* __restrict__ Phit, const float* __restrict__ Phis,
    const float* __restrict__ Pt,   const float* __restrict__ Psrf,
    const float* __restrict__ U0, const float* __restrict__ V0, const float* __restrict__ W0,
    const float* __restrict__ T0, const float* __restrict__ M0, const float* __restrict__ P0,
    float* __restrict__ Uo, float* __restrict__ Vo, float* __restrict__ Wo,
    float* __restrict__ To, float* __restrict__ Mo, float* __restrict__ Po,
    const int* __restrict__ dtp, float coef)
{
    const int i = blockIdx.x * blockDim.x + threadIdx.x;
    const int j = blockIdx.y;
    const int k = blockIdx.z;
    if (i >= NXc) return;
    const float c = coef * (float)(*dtp);

    // ---- accessors (all reads; compiler CSEs duplicates) ----
    auto MU   = [&](int kk, int jj, int ii) -> float { return Ms[(kk * NYc + jj) * NXc + ii]; };
    auto TH   = [&](int kk, int jj, int ii) -> float {
        const int id = (kk * NYc + jj) * NXc + ii; return Ts[id] * frcp(Ms[id]); };
    auto PR   = [&](int kk, int jj, int ii) -> float { return prs[(kk * NYc + jj) * NXc + ii]; };
    auto UF   = [&](int kk, int jj, int II) -> float { return Us[(kk * NYc + jj) * (NXc + 1) + II]; };
    auto VF   = [&](int kk, int JJ, int ii) -> float { return Vs[(kk * (NYc + 1) + JJ) * NXc + ii]; };
    auto WF   = [&](int kk, int jj, int ii) -> float { return Ws[(kk * NYc + jj) * NXc + ii]; };
    auto PHIh = [&](int kk, int jj, int ii) -> float { return Ps[(kk * NYc + jj) * NXc + ii]; };
    auto PHIP = [&](int kk, int jj, int ii) -> float {
        if (kk <= 0)   return Phit[jj * NXc + ii];
        if (kk >= NZc) return Phis[jj * NXc + ii];
        return Ps[((kk - 1) * NYc + jj) * NXc + ii]; };
    auto OMP  = [&](int kk, int jj, int ii) -> float {   // pad_z(Omega), levels 0..NZ
        if (kk <= 0 || kk >= NZc) return 0.0f;
        return Omg[((kk - 1) * NYc + jj) * NXc + ii]; };
    auto MUX  = [&](int kk, int jj, int II) -> float {   // x-staggered Mu, II in 0..NX
        const int a = (II == 0) ? NXc - 1 : II - 1;
        const int b = (II == NXc) ? 0 : II;
        return 0.5f * (MU(kk, jj, a) + MU(kk, jj, b)); };
    auto UU   = [&](int kk, int jj, int II) -> float { return UF(kk, jj, II) * frcp(MUX(kk, jj, II)); };
    auto MUY  = [&](int kk, int JJ, int ii) -> float {   // y-staggered Mu, JJ in 0..NY
        const int a = (JJ == 0) ? NYc - 1 : JJ - 1;
        const int b = (JJ == NYc) ? 0 : JJ;
        return 0.5f * (MU(kk, a, ii) + MU(kk, b, ii)); };
    auto VV   = [&](int kk, int JJ, int ii) -> float { return VF(kk, JJ, ii) * frcp(MUY(kk, JJ, ii)); };
    auto MUZ  = [&](int kk, int jj, int ii) -> float {   // z-staggered Mu, kk in 0..NZ-2
        return 0.5f * (MU(kk, jj, ii) + MU(kk + 1, jj, ii)); };
    auto WW   = [&](int kk, int jj, int ii) -> float { return WF(kk, jj, ii) * frcp(MUZ(kk, jj, ii)); };
    auto ALPH = [&](int kk, int jj, int ii) -> float {
        return -(PHIP(kk + 1, jj, ii) - PHIP(kk, jj, ii)) * RDZ * frcp(MU(kk, jj, ii)); };

    // ---- R_U at staggered column II (0..NX) ----
    auto R_U_at = [&](int II) -> float {
        const int kk = k, jj = j;
        const int Im1 = (II - 1 < 0) ? NXc : II - 1;   // wrapped u/U index (-1 -> NX)
        const int Ip1 = (II + 1 > NXc) ? 0 : II + 1;   // (NX+1 -> 0)
        const int xa = (II == 0) ? NXc - 1 : II - 1;   // unstaggered col left
        const int xb = (II == NXc) ? 0 : II;           // unstaggered col right
        const int jm = (jj == 0) ? NYc - 1 : jj - 1;
        const int jp = (jj == NYc - 1) ? 0 : jj + 1;

        const float U_m1 = UF(kk, jj, Im1), U_0 = UF(kk, jj, II), U_p1 = UF(kk, jj, Ip1);
        const float u_m1 = UU(kk, jj, Im1), u_0 = UU(kk, jj, II), u_p1 = UU(kk, jj, Ip1);
        const float rx = -(0.25f * (U_0 + U_p1) * (u_0 + u_p1)
                         - 0.25f * (U_m1 + U_0) * (u_m1 + u_0)) * RDX;

        const float VBj  = 0.5f * (VF(kk, jj,     xa) + VF(kk, jj,     xb));
        const float VBj1 = 0.5f * (VF(kk, jj + 1, xa) + VF(kk, jj + 1, xb));
        const float uyj  = 0.5f * (UU(kk, jm, II) + u_0);
        const float uyj1 = 0.5f * (u_0 + UU(kk, jp, II));
        const float ry = -(VBj1 * uyj1 - VBj * uyj) * RDY;

        const float OBk  = 0.5f * (OMP(kk,     jj, xa) + OMP(kk,     jj, xb));
        const float OBk1 = 0.5f * (OMP(kk + 1, jj, xa) + OMP(kk + 1, jj, xb));
        const float uzk  = (kk == 0)       ? 0.5f * u_0 : 0.5f * (UU(kk - 1, jj, II) + u_0);
        const float uzk1 = (kk == NZc - 1) ? 0.5f * u_0 : 0.5f * (u_0 + UU(kk + 1, jj, II));
        const float rz = -(OBk1 * uzk1 - OBk * uzk) * RDZ;

        const float mux = MUX(kk, jj, II);
        const float alx = 0.5f * (ALPH(kk, jj, xa) + ALPH(kk, jj, xb));
        const float dpx = (PR(kk, jj, xb) - PR(kk, jj, xa)) * RDX;
        const float pg1 = -mux * alx * dpx;

        auto PPc = [&](int kh, int col) -> float {      // pad_z(p,P_t,P_s), levels 0..NZ+1
            if (kh <= 0)       return Pt[jj * NXc + col];
            if (kh >= NZc + 1) return Psrf[jj * NXc + col];
            return PR(kh - 1, jj, col); };
        const float pzx_k  = 0.25f * (PPc(kk, xa) + PPc(kk + 1, xa) + PPc(kk, xb) + PPc(kk + 1, xb));
        const float pzx_k1 = 0.25f * (PPc(kk + 1, xa) + PPc(kk + 2, xa) + PPc(kk + 1, xb) + PPc(kk + 2, xb));
        const float dpz = (pzx_k1 - pzx_k) * RDZ;
        const float phiz_a = 0.5f * (PHIP(kk, jj, xa) + PHIP(kk + 1, jj, xa));
        const float phiz_b = 0.5f * (PHIP(kk, jj, xb) + PHIP(kk + 1, jj, xb));
        const float pg2 = -dpz * (phiz_b - phiz_a) * RDX;

        return rx + ry + rz + pg1 + pg2;
    };

    // ---- R_V at staggered row JJ (0..NY) ----
    auto R_V_at = [&](int JJ) -> float {
        const int kk = k, ii = i;
        const int Jm1 = (JJ - 1 < 0) ? NYc : JJ - 1;
        const int Jp1 = (JJ + 1 > NYc) ? 0 : JJ + 1;
        const int ya = (JJ == 0) ? NYc - 1 : JJ - 1;
        const int yb = (JJ == NYc) ? 0 : JJ;
        const int im = (ii == 0) ? NXc - 1 : ii - 1;
        const int ip = (ii == NXc - 1) ? 0 : ii + 1;

        const float V_m1 = VF(kk, Jm1, ii), V_0 = VF(kk, JJ, ii), V_p1 = VF(kk, Jp1, ii);
        const float v_m1 = VV(kk, Jm1, ii), v_0 = VV(kk, JJ, ii), v_p1 = VV(kk, Jp1, ii);
        const float ry = -(0.25f * (V_0 + V_p1) * (v_0 + v_p1)
                         - 0.25f * (V_m1 + V_0) * (v_m1 + v_0)) * RDY;

        const float UBi  = 0.5f * (UF(kk, ya, ii)     + UF(kk, yb, ii));
        const float UBi1 = 0.5f * (UF(kk, ya, ii + 1) + UF(kk, yb, ii + 1));
        const float vxi  = 0.5f * (VV(kk, JJ, im) + v_0);
        const float vxi1 = 0.5f * (v_0 + VV(kk, JJ, ip));
        const float rx = -(UBi1 * vxi1 - UBi * vxi) * RDX;

        const float OBk  = 0.5f * (OMP(kk,     ya, ii) + OMP(kk,     yb, ii));
        const float OBk1 = 0.5f * (OMP(kk + 1, ya, ii) + OMP(kk + 1, yb, ii));
        const float vzk  = (kk == 0)       ? 0.5f * v_0 : 0.5f * (VV(kk - 1, JJ, ii) + v_0);
        const float vzk1 = (kk == NZc - 1) ? 0.5f * v_0 : 0.5f * (v_0 + VV(kk + 1, JJ, ii));
        const float rz = -(OBk1 * vzk1 - OBk * vzk) * RDZ;

        const float muy = MUY(kk, JJ, ii);
        const float aly = 0.5f * (ALPH(kk, ya, ii) + ALPH(kk, yb, ii));
        const float dpy = (PR(kk, yb, ii) - PR(kk, ya, ii)) * RDY;
        const float pg1 = -muy * aly * dpy;

        auto PPr = [&](int kh, int row) -> float {
            if (kh <= 0)       return Pt[row * NXc + ii];
            if (kh >= NZc + 1) return Psrf[row * NXc + ii];
            return PR(kh - 1, row, ii); };
        const float pzy_k  = 0.25f * (PPr(kk, ya) + PPr(kk + 1, ya) + PPr(kk, yb) + PPr(kk + 1, yb));
        const float pzy_k1 = 0.25f * (PPr(kk + 1, ya) + PPr(kk + 2, ya) + PPr(kk + 1, yb) + PPr(kk + 2, yb));
        const float dpz = (pzy_k1 - pzy_k) * RDZ;
        const float phiz_a = 0.5f * (PHIP(kk, ya, ii) + PHIP(kk + 1, ya, ii));
        const float phiz_b = 0.5f * (PHIP(kk, yb, ii) + PHIP(kk + 1, yb, ii));
        const float pg2 = -dpz * (phiz_b - phiz_a) * RDY;

        return rx + ry + rz + pg1 + pg2;
    };

    // ---- R_Theta at (k,j,i) ----
    auto R_T_at = [&]() -> float {
        const int kk = k, jj = j, ii = i;
        const int im = (ii == 0) ? NXc - 1 : ii - 1;
        const int ip = (ii == NXc - 1) ? 0 : ii + 1;
        const int jm = (jj == 0) ? NYc - 1 : jj - 1;
        const int jp = (jj == NYc - 1) ? 0 : jj + 1;
        const float th0 = TH(kk, jj, ii);
        const float rx = -(UF(kk, jj, ii + 1) * 0.5f * (th0 + TH(kk, jj, ip))
                         - UF(kk, jj, ii)     * 0.5f * (TH(kk, jj, im) + th0)) * RDX;
        const float ry = -(VF(kk, jj + 1, ii) * 0.5f * (th0 + TH(kk, jp, ii))
                         - VF(kk, jj, ii)     * 0.5f * (TH(kk, jm, ii) + th0)) * RDY;
        const float Hk  = (kk == 0)       ? 0.0f : OMP(kk, jj, ii)     * 0.5f * (TH(kk - 1, jj, ii) + th0);
        const float Hk1 = (kk == NZc - 1) ? 0.0f : OMP(kk + 1, jj, ii) * 0.5f * (th0 + TH(kk + 1, jj, ii));
        const float rz = -(Hk1 - Hk) * RDZ;
        return rx + ry + rz;
    };

    // ---- R_W at (k,j,i), k in 0..NZ-2 ----
    auto R_W_at = [&]() -> float {
        const int kk = k, jj = j, ii = i;
        const int im = (ii == 0) ? NXc - 1 : ii - 1;
        const int ip = (ii == NXc - 1) ? 0 : ii + 1;
        const int jm = (jj == 0) ? NYc - 1 : jj - 1;
        const int jp = (jj == NYc - 1) ? 0 : jj + 1;
        const float w_0 = WW(kk, jj, ii);
        const float Uzi  = 0.5f * (UF(kk, jj, ii)     + UF(kk + 1, jj, ii));
        const float Uzi1 = 0.5f * (UF(kk, jj, ii + 1) + UF(kk + 1, jj, ii + 1));
        const float wxi  = 0.5f * (WW(kk, jj, im) + w_0);
        const float wxi1 = 0.5f * (w_0 + WW(kk, jj, ip));
        const float rx = -(Uzi1 * wxi1 - Uzi * wxi) * RDX;
        const float Vzj  = 0.5f * (VF(kk, jj, ii)     + VF(kk + 1, jj, ii));
        const float Vzj1 = 0.5f * (VF(kk, jj + 1, ii) + VF(kk + 1, jj + 1, ii));
        const float wyj  = 0.5f * (WW(kk, jm, ii) + w_0);
        const float wyj1 = 0.5f * (w_0 + WW(kk, jp, ii));
        const float ry = -(Vzj1 * wyj1 - Vzj * wyj) * RDY;
        const float OZk  = 0.5f * (OMP(kk, jj, ii)     + OMP(kk + 1, jj, ii));
        const float OZk1 = 0.5f * (OMP(kk + 1, jj, ii) + OMP(kk + 2, jj, ii));
        const float wzk  = (kk == 0)       ? 0.5f * w_0 : 0.5f * (WW(kk - 1, jj, ii) + w_0);
        const float wzk1 = (kk == NZc - 2) ? 0.5f * w_0 : 0.5f * (w_0 + WW(kk + 1, jj, ii));
        const float rz = -(OZk1 * wzk1 - OZk * wzk) * RDZ;
        const float bu = Gf * ((PR(kk + 1, jj, ii) - PR(kk, jj, ii)) * RDZ - MUZ(kk, jj, ii));
        return rx + ry + rz + bu;
    };

    // ---- R_Phi at (k,j,i), k in 0..NZ-2 ----
    auto R_P_at = [&]() -> float {
        const int kk = k, jj = j, ii = i;
        const int im = (ii == 0) ? NXc - 1 : ii - 1;
        const int ip = (ii == NXc - 1) ? 0 : ii + 1;
        const int jm = (jj == 0) ? NYc - 1 : jj - 1;
        const int jp = (jj == NYc - 1) ? 0 : jj + 1;
        const float ubz = 0.25f * (UU(kk, jj, ii) + UU(kk, jj, ii + 1)
                                 + UU(kk + 1, jj, ii) + UU(kk + 1, jj, ii + 1));
        const float dfx = (PHIh(kk, jj, ip) - PHIh(kk, jj, im)) * (0.5f * RDX);
        const float vbz = 0.25f * (VV(kk, jj, ii) + VV(kk, jj + 1, ii)
                                 + VV(kk + 1, jj, ii) + VV(kk + 1, jj + 1, ii));
        const float dfy = (PHIh(kk, jp, ii) - PHIh(kk, jm, ii)) * (0.5f * RDY);
        const float rmuz = frcp(MUZ(kk, jj, ii));
        const float om  = OMP(kk + 1, jj, ii) * rmuz;    // omega = Omega/bar_z(Mu)
        const float dfz = (PHIP(kk + 2, jj, ii) - PHIP(kk, jj, ii)) * (0.5f * RDZ);
        const float w_  = WF(kk, jj, ii) * rmuz;
        return -ubz * dfx - vbz * dfy - om * dfz + Gf * w_;
    };

    // ---- R_Mu ----
    const float rMu = -(UF(k, j, i + 1) - UF(k, j, i)) * RDX
                      -(VF(k, j + 1, i) - VF(k, j, i)) * RDY
                      -(OMP(k + 1, j, i) - OMP(k, j, i)) * RDZ;

    // ---- stage updates from ORIGINAL state ----
    const int idc = (k * NYc + j) * NXc + i;
    To[idc] = T0[idc] + c * R_T_at();
    Mo[idc] = M0[idc] + c * rMu;

    const int idu = (k * NYc + j) * (NXc + 1) + i;
    Uo[idu] = U0[idu] + c * R_U_at(i);
    if (i == NXc - 1) {
        Uo[idu + 1] = U0[idu + 1] + c * R_U_at(NXc);
    }

    const int idv = (k * (NYc + 1) + j) * NXc + i;
    Vo[idv] = V0[idv] + c * R_V_at(j);
    if (j == NYc - 1) {
        const int idv2 = (k * (NYc + 1) + NYc) * NXc + i;
        Vo[idv2] = V0[idv2] + c * R_V_at(NYc);
    }

    if (k < NZc - 1) {
        Wo[idc] = W0[idc] + c * R_W_at();
        Po[idc] = P0[idc] + c * R_P_at();
    }
}

} // anonymous namespace

extern "C" void kernel_launch(void* const* d_in, const int* in_sizes, int n_in,
                              void* d_out, int out_size, void* d_ws, size_t ws_size,
                              hipStream_t stream)
{
    (void)in_sizes; (void)n_in; (void)out_size; (void)ws_size;

    const float* U0   = (const float*)d_in[0];
    const float* V0   = (const float*)d_in[1];
    const float* W0   = (const float*)d_in[2];
    const float* T0   = (const float*)d_in[3];
    const float* M0   = (const float*)d_in[4];
    const float* P0   = (const float*)d_in[5];
    const float* Phit = (const float*)d_in[6];
    const float* Phis = (const float*)d_in[7];
    const float* Pt   = (const float*)d_in[8];
    const float* Psrf = (const float*)d_in[9];
    const int*   dtp  = (const int*)d_in[10];

    float* out = (float*)d_out;
    float* ws  = (float*)d_ws;

    float* outU = out;
    float* outV = outU + SZ_U;
    float* outW = outV + SZ_V;
    float* outT = outW + SZ_W;
    float* outM = outT + SZ_T;
    float* outP = outM + SZ_M;

    float* wsU = ws;
    float* wsV = wsU + SZ_U;
    float* wsW = wsV + SZ_V;
    float* wsT = wsW + SZ_W;
    float* wsM = wsT + SZ_T;
    float* wsP = wsM + SZ_M;

    float* prs = ws + SZ_STATE;       // p  : NZ*NY*NX
    float* Omg = prs + SZ_T;          // Omega : (NZ-1)*NY*NX

    const dim3 blk(128, 1, 1);
    const dim3 grd(NXc / 128, NYc, NZc);

    const float coefs[3] = {1.0f / 3.0f, 0.5f, 1.0f};

    // stage ping-pong: d_in -> d_out -> ws -> d_out
    const float* sU[3] = {U0, outU, wsU};
    const float* sV[3] = {V0, outV, wsV};
    const float* sW[3] = {W0, outW, wsW};
    const float* sT[3] = {T0, outT, wsT};
    const float* sM[3] = {M0, outM, wsM};
    const float* sP[3] = {P0, outP, wsP};
    float* oU[3] = {outU, wsU, outU};
    float* oV[3] = {outV, wsV, outV};
    float* oW[3] = {outW, wsW, outW};
    float* oT[3] = {outT, wsT, outT};
    float* oM[3] = {outM, wsM, outM};
    float* oP[3] = {outP, wsP, outP};

    for (int s = 0; s < 3; ++s) {
        prep_kernel<<<grd, blk, 0, stream>>>(sT[s], sM[s], sP[s], sW[s], Phit, Phis, prs, Omg);
        rhs_kernel<<<grd, blk, 0, stream>>>(
            sU[s], sV[s], sW[s], sT[s], sM[s], sP[s],
            prs, Omg, Phit, Phis, Pt, Psrf,
            U0, V0, W0, T0, M0, P0,
            oU[s], oV[s], oW[s], oT[s], oM[s], oP[s],
            dtp, coefs[s]);
    }
}

// Round 5
// 730.112 us; speedup vs baseline: 5.2505x; 1.3145x over previous
//
#include <hip/hip_runtime.h>

namespace {

constexpr int NXc = 384, NYc = 384, NZc = 48;
constexpr int NXU = NXc + 1;
constexpr float RDX = 1.0f / 1000.0f;     // 1/DX
constexpr float RDY = 1.0f / 1000.0f;     // 1/DY
constexpr float RDZ = 49.0f;              // 1/DZ, DZ = 1/(NZ+1)
constexpr float PREFf = 100000.0f, RDf = 287.0f, Gf = 9.81f;
constexpr float K_RP = RDf / PREFf;

constexpr int PLN  = NYc * NXc;
constexpr int SZ_U = NZc * NYc * NXU;
constexpr int SZ_V = NZc * (NYc + 1) * NXc;
constexpr int SZ_W = (NZc - 1) * PLN;
constexpr int SZ_T = NZc * PLN;
constexpr int SZ_M = NZc * PLN;
constexpr int SZ_P = (NZc - 1) * PLN;
constexpr int SZ_STATE = SZ_U + SZ_V + SZ_W + SZ_T + SZ_M + SZ_P;

// tile geometry
constexpr int TX = 32, TY = 8;            // 256 threads, cells per tile
constexpr int PW = TX + 3;                // plane width  35 (cols i0-1 .. i0+33)
constexpr int PH = TY + 3;                // plane height 11 (rows j0-1 .. j0+9)
constexpr int PSZ = PW * PH;              // 385
constexpr int KCH = 12, KSPLIT = 4;       // k-march per block

// field indices in LDS
enum { FPH = 0, FMU, FAL, FTH, FP, Fu, FUR, Fv, FVR, Fw, FOM, NFLD };

__device__ __forceinline__ float frcp(float x) { return __builtin_amdgcn_rcpf(x); }
__device__ __forceinline__ float pow14(float x) {
    return __builtin_amdgcn_exp2f(1.4f * __builtin_amdgcn_logf(x));   // x^1.4, base-2 HW ops
}

__global__ __launch_bounds__(256, 3)
void rhs_tile(
    const float* __restrict__ Us, const float* __restrict__ Vs, const float* __restrict__ Ws,
    const float* __restrict__ Ts, const float* __restrict__ Ms, const float* __restrict__ Ps,
    const float* __restrict__ Phit, const float* __restrict__ Phis,
    const float* __restrict__ Pt,   const float* __restrict__ Psrf,
    const float* __restrict__ U0, const float* __restrict__ V0, const float* __restrict__ W0,
    const float* __restrict__ T0, const float* __restrict__ M0, const float* __restrict__ P0,
    float* __restrict__ Uo, float* __restrict__ Vo, float* __restrict__ Wo,
    float* __restrict__ To, float* __restrict__ Mo, float* __restrict__ Po,
    const int* __restrict__ dtp, float coef)
{
    const int tx = threadIdx.x, ty = threadIdx.y;
    const int tid = ty * TX + tx;
    const int i0 = blockIdx.x * TX;
    const int j0 = blockIdx.y * TY;
    const int k0 = blockIdx.z * KCH;
    const int i = i0 + tx, j = j0 + ty;
    const float c = coef * (float)(*dtp);

    __shared__ float sm[NFLD][3][PSZ];

    // ---- cooperative fill of all planes at level lvl into ring slot ----
    auto fill = [&](int lvl, int slot) {
        for (int idx = tid; idx < PSZ; idx += 256) {
            const int r  = idx / PW;
            const int cc = idx - r * PW;
            int gj = j0 - 1 + r;  if (gj < 0) gj += NYc; else if (gj >= NYc) gj -= NYc;
            int gi = i0 - 1 + cc; if (gi < 0) gi += NXc; else if (gi >= NXc) gi -= NXc;
            int gII = i0 - 1 + cc; if (gII < 0) gII += NXc + 1; else if (gII > NXc) gII -= NXc + 1;
            int gJJ = j0 - 1 + r;  if (gJJ < 0) gJJ += NYc + 1; else if (gJJ > NYc) gJJ -= NYc + 1;
            const int pix = gj * NXc + gi;

            const int lc = (lvl < 0) ? 0 : ((lvl > NZc - 1) ? NZc - 1 : lvl);
            const float muv = Ms[lc * PLN + pix];
            const float phv = (lvl < 0) ? Phit[pix]
                             : ((lvl >= NZc - 1) ? Phis[pix] : Ps[lvl * PLN + pix]);

            float thv = 0.f, alv = 1.f, pv;
            float uv = 0.f, Uv = 0.f, vv = 0.f, Vv = 0.f, wv = 0.f, omv = 0.f;

            if (lvl >= 0 && lvl < NZc) {
                const float phm = (lvl == 0) ? Phit[pix] : Ps[(lvl - 1) * PLN + pix];
                alv = -(phv - phm) * RDZ * frcp(muv);
                thv = Ts[lvl * PLN + pix] * frcp(muv);
                pv  = PREFf * pow14(K_RP * thv * frcp(alv));

                Uv = Us[(lvl * NYc + gj) * NXU + gII];
                const int xa = (gII == 0)   ? NXc - 1 : gII - 1;
                const int xb = (gII == NXc) ? 0       : gII;
                uv = Uv * frcp(0.5f * (Ms[lvl * PLN + gj * NXc + xa]
                                     + Ms[lvl * PLN + gj * NXc + xb]));

                Vv = Vs[(lvl * (NYc + 1) + gJJ) * NXc + gi];
                const int ya = (gJJ == 0)   ? NYc - 1 : gJJ - 1;
                const int yb = (gJJ == NYc) ? 0       : gJJ;
                vv = Vv * frcp(0.5f * (Ms[lvl * PLN + ya * NXc + gi]
                                     + Ms[lvl * PLN + yb * NXc + gi]));

                if (lvl < NZc - 1) {
                    const float mu1 = Ms[(lvl + 1) * PLN + pix];
                    const float Wv  = Ws[lvl * PLN + pix];
                    wv = Wv * frcp(0.5f * (muv + mu1));
                    const float ph1 = (lvl + 1 >= NZc - 1) ? Phis[pix] : Ps[(lvl + 1) * PLN + pix];
                    const float al1 = -(ph1 - phv) * RDZ * frcp(mu1);
                    omv = -Wv * Gf * frcp(0.5f * (alv + al1) * 0.5f * (muv + mu1));
                }
            } else {
                pv = (lvl < 0) ? Pt[pix] : Psrf[pix];   // p[-1]=P_t, p[NZ]=P_s (pad_z of p)
            }

            sm[FPH][slot][idx] = phv;  sm[FMU][slot][idx] = muv;
            sm[FAL][slot][idx] = alv;  sm[FTH][slot][idx] = thv;
            sm[FP ][slot][idx] = pv;
            sm[Fu ][slot][idx] = uv;   sm[FUR][slot][idx] = Uv;
            sm[Fv ][slot][idx] = vv;   sm[FVR][slot][idx] = Vv;
            sm[Fw ][slot][idx] = wv;   sm[FOM][slot][idx] = omv;
        }
    };

    const int ly = ty + 1, lx = tx + 1;

    int s0 = 0, s1 = 1, s2 = 2;
    fill(k0 - 1, 0);
    fill(k0, 1);

    for (int k = k0; k < k0 + KCH; ++k) {
        fill(k + 1, s2);
        __syncthreads();

        auto SV = [&](int f, int s, int r, int cc2) -> float {
            return sm[f][s][r * PW + cc2];
        };

        // ---- R_U at staggered plane-column cc (u cols cc-1..cc+1, cells cc-1,cc) ----
        auto R_U_c = [&](int cc) -> float {
            const float u0  = SV(Fu, s1, ly, cc);
            const float um  = SV(Fu, s1, ly, cc - 1), up = SV(Fu, s1, ly, cc + 1);
            const float U0v = SV(FUR, s1, ly, cc);
            const float Umv = SV(FUR, s1, ly, cc - 1), Upv = SV(FUR, s1, ly, cc + 1);
            float r = -0.25f * ((U0v + Upv) * (u0 + up) - (Umv + U0v) * (um + u0)) * RDX;
            const float VBj  = 0.5f * (SV(FVR, s1, ly,     cc - 1) + SV(FVR, s1, ly,     cc));
            const float VBj1 = 0.5f * (SV(FVR, s1, ly + 1, cc - 1) + SV(FVR, s1, ly + 1, cc));
            const float uS = SV(Fu, s1, ly - 1, cc), uN = SV(Fu, s1, ly + 1, cc);
            r -= (VBj1 * 0.5f * (u0 + uN) - VBj * 0.5f * (uS + u0)) * RDY;
            const float OBk  = 0.5f * (SV(FOM, s0, ly, cc - 1) + SV(FOM, s0, ly, cc));
            const float OBk1 = 0.5f * (SV(FOM, s1, ly, cc - 1) + SV(FOM, s1, ly, cc));
            const float ukm = SV(Fu, s0, ly, cc), ukp = SV(Fu, s2, ly, cc);
            r -= (OBk1 * 0.5f * (u0 + ukp) - OBk * 0.5f * (ukm + u0)) * RDZ;
            const float mux = 0.5f * (SV(FMU, s1, ly, cc - 1) + SV(FMU, s1, ly, cc));
            const float alx = 0.5f * (SV(FAL, s1, ly, cc - 1) + SV(FAL, s1, ly, cc));
            const float dpx = (SV(FP, s1, ly, cc) - SV(FP, s1, ly, cc - 1)) * RDX;
            r -= mux * alx * dpx;
            const float pzk  = 0.25f * (SV(FP, s0, ly, cc - 1) + SV(FP, s1, ly, cc - 1)
                                      + SV(FP, s0, ly, cc)     + SV(FP, s1, ly, cc));
            const float pzk1 = 0.25f * (SV(FP, s1, ly, cc - 1) + SV(FP, s2, ly, cc - 1)
                                      + SV(FP, s1, ly, cc)     + SV(FP, s2, ly, cc));
            const float dpz = (pzk1 - pzk) * RDZ;
            const float pza = 0.5f * (SV(FPH, s0, ly, cc - 1) + SV(FPH, s1, ly, cc - 1));
            const float pzb = 0.5f * (SV(FPH, s0, ly, cc)     + SV(FPH, s1, ly, cc));
            r -= dpz * (pzb - pza) * RDX;
            return r;
        };

        // ---- R_V at staggered plane-row rr (v rows rr-1..rr+1, cell rows rr-1,rr) ----
        auto R_V_c = [&](int rr) -> float {
            const float v0  = SV(Fv, s1, rr, lx);
            const float vm  = SV(Fv, s1, rr - 1, lx), vp = SV(Fv, s1, rr + 1, lx);
            const float V0v = SV(FVR, s1, rr, lx);
            const float Vmv = SV(FVR, s1, rr - 1, lx), Vpv = SV(FVR, s1, rr + 1, lx);
            float r = -0.25f * ((V0v + Vpv) * (v0 + vp) - (Vmv + V0v) * (vm + v0)) * RDY;
            const float UBi  = 0.5f * (SV(FUR, s1, rr - 1, lx)     + SV(FUR, s1, rr, lx));
            const float UBi1 = 0.5f * (SV(FUR, s1, rr - 1, lx + 1) + SV(FUR, s1, rr, lx + 1));
            const float vW = SV(Fv, s1, rr, lx - 1), vE = SV(Fv, s1, rr, lx + 1);
            r -= (UBi1 * 0.5f * (v0 + vE) - UBi * 0.5f * (vW + v0)) * RDX;
            const float OBk  = 0.5f * (SV(FOM, s0, rr - 1, lx) + SV(FOM, s0, rr, lx));
            const float OBk1 = 0.5f * (SV(FOM, s1, rr - 1, lx) + SV(FOM, s1, rr, lx));
            const float vkm = SV(Fv, s0, rr, lx), vkp = SV(Fv, s2, rr, lx);
            r -= (OBk1 * 0.5f * (v0 + vkp) - OBk * 0.5f * (vkm + v0)) * RDZ;
            const float muy = 0.5f * (SV(FMU, s1, rr - 1, lx) + SV(FMU, s1, rr, lx));
            const float aly = 0.5f * (SV(FAL, s1, rr - 1, lx) + SV(FAL, s1, rr, lx));
            const float dpy = (SV(FP, s1, rr, lx) - SV(FP, s1, rr - 1, lx)) * RDY;
            r -= muy * aly * dpy;
            const float pzk  = 0.25f * (SV(FP, s0, rr - 1, lx) + SV(FP, s1, rr - 1, lx)
                                      + SV(FP, s0, rr, lx)     + SV(FP, s1, rr, lx));
            const float pzk1 = 0.25f * (SV(FP, s1, rr - 1, lx) + SV(FP, s2, rr - 1, lx)
                                      + SV(FP, s1, rr, lx)     + SV(FP, s2, rr, lx));
            const float dpz = (pzk1 - pzk) * RDZ;
            const float pza = 0.5f * (SV(FPH, s0, rr - 1, lx) + SV(FPH, s1, rr - 1, lx));
            const float pzb = 0.5f * (SV(FPH, s0, rr, lx)     + SV(FPH, s1, rr, lx));
            r -= dpz * (pzb - pza) * RDY;
            return r;
        };

        // ===== R_Theta =====
        const float th0 = SV(FTH, s1, ly, lx);
        float rT = -(SV(FUR, s1, ly, lx + 1) * 0.5f * (th0 + SV(FTH, s1, ly, lx + 1))
                   - SV(FUR, s1, ly, lx)     * 0.5f * (SV(FTH, s1, ly, lx - 1) + th0)) * RDX
                   -(SV(FVR, s1, ly + 1, lx) * 0.5f * (th0 + SV(FTH, s1, ly + 1, lx))
                   - SV(FVR, s1, ly, lx)     * 0.5f * (SV(FTH, s1, ly - 1, lx) + th0)) * RDY;
        const float Hk  = SV(FOM, s0, ly, lx) * 0.5f * (SV(FTH, s0, ly, lx) + th0);
        const float Hk1 = SV(FOM, s1, ly, lx) * 0.5f * (th0 + SV(FTH, s2, ly, lx));
        rT -= (Hk1 - Hk) * RDZ;

        // ===== R_Mu =====
        const float rM = -(SV(FUR, s1, ly, lx + 1) - SV(FUR, s1, ly, lx)) * RDX
                         -(SV(FVR, s1, ly + 1, lx) - SV(FVR, s1, ly, lx)) * RDY
                         -(SV(FOM, s1, ly, lx)     - SV(FOM, s0, ly, lx)) * RDZ;

        // ===== stores (center) =====
        const int idc = (k * NYc + j) * NXc + i;
        To[idc] = T0[idc] + c * rT;
        Mo[idc] = M0[idc] + c * rM;
        const int idu = (k * NYc + j) * NXU + i;
        Uo[idu] = U0[idu] + c * R_U_c(lx);
        const int idv = (k * (NYc + 1) + j) * NXc + i;
        Vo[idv] = V0[idv] + c * R_V_c(ly);

        // ===== R_W / R_Phi at half level k (k < NZ-1) =====
        if (k < NZc - 1) {
            const float w0 = SV(Fw, s1, ly, lx);
            const float Uzi  = 0.5f * (SV(FUR, s1, ly, lx)     + SV(FUR, s2, ly, lx));
            const float Uzi1 = 0.5f * (SV(FUR, s1, ly, lx + 1) + SV(FUR, s2, ly, lx + 1));
            const float wW = SV(Fw, s1, ly, lx - 1), wE = SV(Fw, s1, ly, lx + 1);
            float rW = -(Uzi1 * 0.5f * (w0 + wE) - Uzi * 0.5f * (wW + w0)) * RDX;
            const float Vzj  = 0.5f * (SV(FVR, s1, ly, lx)     + SV(FVR, s2, ly, lx));
            const float Vzj1 = 0.5f * (SV(FVR, s1, ly + 1, lx) + SV(FVR, s2, ly + 1, lx));
            const float wS = SV(Fw, s1, ly - 1, lx), wN = SV(Fw, s1, ly + 1, lx);
            rW -= (Vzj1 * 0.5f * (w0 + wN) - Vzj * 0.5f * (wS + w0)) * RDY;
            const float OZk  = 0.5f * (SV(FOM, s0, ly, lx) + SV(FOM, s1, ly, lx));
            const float OZk1 = 0.5f * (SV(FOM, s1, ly, lx) + SV(FOM, s2, ly, lx));
            const float wkm = SV(Fw, s0, ly, lx), wkp = SV(Fw, s2, ly, lx);
            rW -= (OZk1 * 0.5f * (w0 + wkp) - OZk * 0.5f * (wkm + w0)) * RDZ;
            const float muz = 0.5f * (SV(FMU, s1, ly, lx) + SV(FMU, s2, ly, lx));
            rW += Gf * ((SV(FP, s2, ly, lx) - SV(FP, s1, ly, lx)) * RDZ - muz);

            const float ubz = 0.25f * (SV(Fu, s1, ly, lx) + SV(Fu, s1, ly, lx + 1)
                                     + SV(Fu, s2, ly, lx) + SV(Fu, s2, ly, lx + 1));
            const float dfx = (SV(FPH, s1, ly, lx + 1) - SV(FPH, s1, ly, lx - 1)) * (0.5f * RDX);
            const float vbz = 0.25f * (SV(Fv, s1, ly, lx) + SV(Fv, s1, ly + 1, lx)
                                     + SV(Fv, s2, ly, lx) + SV(Fv, s2, ly + 1, lx));
            const float dfy = (SV(FPH, s1, ly + 1, lx) - SV(FPH, s1, ly - 1, lx)) * (0.5f * RDY);
            const float rmuz = frcp(muz);
            const float om  = SV(FOM, s1, ly, lx) * rmuz;
            const float dfz = (SV(FPH, s2, ly, lx) - SV(FPH, s0, ly, lx)) * (0.5f * RDZ);
            const float rP = -ubz * dfx - vbz * dfy - om * dfz + Gf * w0;

            Wo[idc] = W0[idc] + c * rW;
            Po[idc] = P0[idc] + c * rP;
        }

        // ===== extra staggered column II=NX / row JJ=NY (pure LDS, same formulas) =====
        if (i == NXc - 1) {
            const int idu2 = idu + 1;
            Uo[idu2] = U0[idu2] + c * R_U_c(lx + 1);
        }
        if (j == NYc - 1) {
            const int idv2 = (k * (NYc + 1) + NYc) * NXc + i;
            Vo[idv2] = V0[idv2] + c * R_V_c(ly + 1);
        }

        __syncthreads();
        const int t = s0; s0 = s1; s1 = s2; s2 = t;
    }
}

} // anonymous namespace

extern "C" void kernel_launch(void* const* d_in, const int* in_sizes, int n_in,
                              void* d_out, int out_size, void* d_ws, size_t ws_size,
                              hipStream_t stream)
{
    (void)in_sizes; (void)n_in; (void)out_size; (void)ws_size;

    const float* U0   = (const float*)d_in[0];
    const float* V0   = (const float*)d_in[1];
    const float* W0   = (const float*)d_in[2];
    const float* T0   = (const float*)d_in[3];
    const float* M0   = (const float*)d_in[4];
    const float* P0   = (const float*)d_in[5];
    const float* Phit = (const float*)d_in[6];
    const float* Phis = (const float*)d_in[7];
    const float* Pt   = (const float*)d_in[8];
    const float* Psrf = (const float*)d_in[9];
    const int*   dtp  = (const int*)d_in[10];

    float* out = (float*)d_out;
    float* ws  = (float*)d_ws;

    float* outU = out;
    float* outV = outU + SZ_U;
    float* outW = outV + SZ_V;
    float* outT = outW + SZ_W;
    float* outM = outT + SZ_T;
    float* outP = outM + SZ_M;

    float* wsU = ws;
    float* wsV = wsU + SZ_U;
    float* wsW = wsV + SZ_V;
    float* wsT = wsW + SZ_W;
    float* wsM = wsT + SZ_T;
    float* wsP = wsM + SZ_M;

    const dim3 blk(TX, TY, 1);
    const dim3 grd(NXc / TX, NYc / TY, KSPLIT);

    const float coefs[3] = {1.0f / 3.0f, 0.5f, 1.0f};

    // stage ping-pong: d_in -> d_out -> ws -> d_out
    const float* sU[3] = {U0, outU, wsU};
    const float* sV[3] = {V0, outV, wsV};
    const float* sW[3] = {W0, outW, wsW};
    const float* sT[3] = {T0, outT, wsT};
    const float* sM[3] = {M0, outM, wsM};
    const float* sP[3] = {P0, outP, wsP};
    float* oU[3] = {outU, wsU, outU};
    float* oV[3] = {outV, wsV, outV};
    float* oW[3] = {outW, wsW, outW};
    float* oT[3] = {outT, wsT, outT};
    float* oM[3] = {outM, wsM, outM};
    float* oP[3] = {outP, wsP, outP};

    for (int s = 0; s < 3; ++s) {
        rhs_tile<<<grd, blk, 0, stream>>>(
            sU[s], sV[s], sW[s], sT[s], sM[s], sP[s],
            Phit, Phis, Pt, Psrf,
            U0, V0, W0, T0, M0, P0,
            oU[s], oV[s], oW[s], oT[s], oM[s], oP[s],
            dtp, coefs[s]);
    }
}